// Round 4
// baseline (124.003 us; speedup 1.0000x reference)
//
#include <hip/hip_runtime.h>
#include <hip/hip_bf16.h>
#include <math.h>

#define NN    8
#define HH    64
#define WW    64
#define HW    4096
#define NHW   32768
#define DALL  384     // 256 value + 112 om + 16 pad
#define EPSBN 1e-5f

typedef __attribute__((ext_vector_type(8))) short short8v;
typedef __attribute__((ext_vector_type(4))) float f32x4;
typedef __attribute__((ext_vector_type(2))) float f32x2;

__device__ __forceinline__ float b2f(unsigned short u) {
    union { unsigned int i; float f; } v; v.i = ((unsigned int)u) << 16; return v.f;
}
__device__ __forceinline__ unsigned short f2b(float f) {
    __hip_bfloat16 h = __float2bfloat16(f);
    return *reinterpret_cast<const unsigned short*>(&h);
}
// dword of 2 bf16 -> f32x2 (lo, hi)
__device__ __forceinline__ f32x2 bf2x(int u) {
    union { int i; float f; } a, b;
    a.i = u << 16;
    b.i = u & 0xffff0000;
    f32x2 r; r[0] = a.f; r[1] = b.f; return r;
}

// Workspace layout (bytes):
//  VO     [NHW][384] bf16  @ 0          (25165824)
//  y      [NHW][256] bf16  @ 25165824   (16777216)
//  Wallbf [384][256] bf16  @ 41943040   (196608)
//  Woutbf [256][256] bf16  @ 42139648   (131072)
//  ball   [384] f32        @ 42270720   (1536)
//  bout   [256] f32        @ 42272256   (1024)

// ---------------- prep: fold weights (f32 math, 4-way ILP) ----------------
__global__ __launch_bounds__(256)
void prep_kernel(const float* __restrict__ cv1_w, const float* __restrict__ cv1_b,
                 const float* __restrict__ value_w, const float* __restrict__ value_b,
                 const float* __restrict__ dw_w, const float* __restrict__ dw_b,
                 const float* __restrict__ om_w, const float* __restrict__ om_b,
                 const float* __restrict__ out_w, const float* __restrict__ cv2_w,
                 const float* __restrict__ bn_g, const float* __restrict__ bn_b,
                 const float* __restrict__ bn_m, const float* __restrict__ bn_v,
                 unsigned short* __restrict__ Wallbf, float* __restrict__ ball,
                 unsigned short* __restrict__ Woutbf, float* __restrict__ bout)
{
    int job = blockIdx.x * 256 + threadIdx.x;
    if (job < 65536) {                          // Wv = value_w @ cv1_w
        int d = job >> 8, cc = job & 255;
        float s0=0.f, s1=0.f, s2=0.f, s3=0.f;
        for (int e = 0; e < 256; e += 4) {
            float4 wv = *reinterpret_cast<const float4*>(&value_w[d*256+e]);
            s0 = fmaf(wv.x, cv1_w[(e+0)*256+cc], s0);
            s1 = fmaf(wv.y, cv1_w[(e+1)*256+cc], s1);
            s2 = fmaf(wv.z, cv1_w[(e+2)*256+cc], s2);
            s3 = fmaf(wv.w, cv1_w[(e+3)*256+cc], s3);
        }
        Wallbf[job] = f2b((s0+s1)+(s2+s3));
    } else if (job < 94208) {                   // Wom = om_w.diag(dw_w) @ cv1_w
        int idx = job - 65536;
        int o = idx >> 8, cc = idx & 255;
        float s0=0.f, s1=0.f, s2=0.f, s3=0.f;
        for (int e = 0; e < 256; e += 4) {
            float4 wv = *reinterpret_cast<const float4*>(&om_w[o*256+e]);
            float4 dv = *reinterpret_cast<const float4*>(&dw_w[e]);
            s0 = fmaf(wv.x*dv.x, cv1_w[(e+0)*256+cc], s0);
            s1 = fmaf(wv.y*dv.y, cv1_w[(e+1)*256+cc], s1);
            s2 = fmaf(wv.z*dv.z, cv1_w[(e+2)*256+cc], s2);
            s3 = fmaf(wv.w*dv.w, cv1_w[(e+3)*256+cc], s3);
        }
        Wallbf[job] = f2b((s0+s1)+(s2+s3));
    } else if (job < 98304) {                   // pad rows 368..383
        Wallbf[job] = 0;
    } else if (job < 163840) {                  // Wout = diag(s) cv2_w @ out_w
        int idx = job - 98304;
        int d = idx >> 8, cc = idx & 255;
        float s0=0.f, s1=0.f, s2=0.f, s3=0.f;
        for (int e = 0; e < 256; e += 4) {
            float4 wv = *reinterpret_cast<const float4*>(&cv2_w[d*256+e]);
            s0 = fmaf(wv.x, out_w[(e+0)*256+cc], s0);
            s1 = fmaf(wv.y, out_w[(e+1)*256+cc], s1);
            s2 = fmaf(wv.z, out_w[(e+2)*256+cc], s2);
            s3 = fmaf(wv.w, out_w[(e+3)*256+cc], s3);
        }
        float sc = bn_g[d] * rsqrtf(bn_v[d] + EPSBN);
        Woutbf[idx] = f2b(((s0+s1)+(s2+s3)) * sc);
    } else if (job < 164096) {                  // bv
        int d = job - 163840;
        float s = value_b[d];
        for (int e = 0; e < 256; ++e) s = fmaf(value_w[d*256+e], cv1_b[e], s);
        ball[d] = s;
    } else if (job < 164208) {                  // bom
        int o = job - 164096;
        float s = om_b[o];
        for (int e = 0; e < 256; ++e)
            s = fmaf(om_w[o*256+e], fmaf(dw_w[e], cv1_b[e], dw_b[e]), s);
        ball[256 + o] = s;
    } else if (job < 164224) {                  // ball pad
        ball[368 + job - 164208] = 0.f;
    } else if (job < 164480) {                  // bout
        int d = job - 164224;
        float sc = bn_g[d] * rsqrtf(bn_v[d] + EPSBN);
        bout[d] = fmaf(-bn_m[d], sc, bn_b[d]);
    }
}

// ---------------- GEMM1 (fused x-transpose): VO = bf16(x)^T @ Wallbf^T + ball ----------------
// A staged straight from NCHW f32 x: lane loads 16 float2 (16 ch x 2 px),
// register-transposes to 4 short8v rows, ds_write_b128 into swizzled As.
__global__ __launch_bounds__(256)
void gemm_vo_kernel(const float* __restrict__ x, const unsigned short* __restrict__ Wallbf,
                    const float* __restrict__ ball, unsigned short* __restrict__ VO)
{
    __shared__ unsigned short As[8192];
    __shared__ unsigned short Bs[8192];
    int t = threadIdx.x;
    int m0 = blockIdx.x * 128;   // pixel tile
    int n0 = blockIdx.y * 128;   // output-channel tile
    int nimg = m0 >> 12, hw0 = m0 & 4095;
    int lane = t & 63;
    int wv = t >> 6;
    int wr = wv >> 1, wc = wv & 1;
    int r_l = lane & 15, kg_l = lane >> 4;
    int ci = t >> 6;             // c-chunk (16 ch) for A staging
    int l  = t & 63;             // row-pair for A staging

    const float* xbase = x + (size_t)(nimg * 256) * 4096 + hw0;

    f32x4 acc[4][4] = {};

    for (int kt = 0; kt < 4; ++kt) {
        int c0 = kt * 64;
        float2 val[16];
        #pragma unroll
        for (int i = 0; i < 16; ++i)
            val[i] = *reinterpret_cast<const float2*>(
                &xbase[(size_t)(c0 + ci*16 + i) * 4096 + 2*l]);
        __syncthreads();   // prior MFMA reads done before overwrite
        #pragma unroll
        for (int rsel = 0; rsel < 2; ++rsel) {
            int row = 2*l + rsel;
            #pragma unroll
            for (int kgi = 0; kgi < 2; ++kgi) {
                int kg = ci*2 + kgi;
                short8v s;
                #pragma unroll
                for (int j = 0; j < 8; ++j)
                    s[j] = (short)f2b(rsel ? val[kgi*8+j].y : val[kgi*8+j].x);
                *reinterpret_cast<short8v*>(&As[row*64 + ((kg ^ (row & 7)) << 3)]) = s;
            }
        }
        #pragma unroll
        for (int i = 0; i < 4; ++i) {
            int idx = t + i*256;
            int row = idx >> 3, kg = idx & 7;
            *reinterpret_cast<short8v*>(&Bs[row*64 + ((kg ^ (row & 7)) << 3)]) =
                *reinterpret_cast<const short8v*>(&Wallbf[(size_t)(n0 + row)*256 + c0 + kg*8]);
        }
        __syncthreads();
        #pragma unroll
        for (int ks = 0; ks < 2; ++ks) {
            short8v af[4], bfr[4];
            #pragma unroll
            for (int m = 0; m < 4; ++m) {
                int row = wr*64 + m*16 + r_l;
                af[m] = *reinterpret_cast<const short8v*>(
                    &As[row*64 + (((ks*4 + kg_l) ^ (row & 7)) << 3)]);
            }
            #pragma unroll
            for (int n = 0; n < 4; ++n) {
                int row = wc*64 + n*16 + r_l;
                bfr[n] = *reinterpret_cast<const short8v*>(
                    &Bs[row*64 + (((ks*4 + kg_l) ^ (row & 7)) << 3)]);
            }
            #pragma unroll
            for (int m = 0; m < 4; ++m)
                #pragma unroll
                for (int n = 0; n < 4; ++n)
                    acc[m][n] = __builtin_amdgcn_mfma_f32_16x16x32_bf16(af[m], bfr[n], acc[m][n], 0, 0, 0);
        }
    }

    #pragma unroll
    for (int n = 0; n < 4; ++n) {
        int d = n0 + wc*64 + n*16 + r_l;
        float bb = ball[d];
        #pragma unroll
        for (int m = 0; m < 4; ++m) {
            int pr = m0 + wr*64 + m*16 + (kg_l << 2);
            #pragma unroll
            for (int r = 0; r < 4; ++r)
                VO[(size_t)(pr + r)*384 + d] = f2b(acc[m][n][r] + bb);
        }
    }
}

// ---------------- GEMM2 (transposed): out = SiLU(Wout @ y^T + bout), NCHW f32 ----------------
__device__ __forceinline__
void gemm_mainloop(const unsigned short* __restrict__ A, const unsigned short* __restrict__ B,
                   int m0, int n0, unsigned short* As, unsigned short* Bs,
                   f32x4 (&acc)[4][4], int t)
{
    int lane = t & 63;
    int wv = t >> 6;
    int wr = wv >> 1, wc = wv & 1;
    int r_l = lane & 15;
    int kg_l = lane >> 4;

    for (int kt = 0; kt < 4; ++kt) {
        int c0 = kt * 64;
        #pragma unroll
        for (int i = 0; i < 4; ++i) {
            int idx = t + i * 256;
            int kg = idx & 7, row = idx >> 3;
            int soff = row*64 + ((kg ^ (row & 7)) << 3);
            *reinterpret_cast<short8v*>(&As[soff]) =
                *reinterpret_cast<const short8v*>(&A[(size_t)(m0 + row)*256 + c0 + kg*8]);
            *reinterpret_cast<short8v*>(&Bs[soff]) =
                *reinterpret_cast<const short8v*>(&B[(size_t)(n0 + row)*256 + c0 + kg*8]);
        }
        __syncthreads();
        #pragma unroll
        for (int ks = 0; ks < 2; ++ks) {
            short8v af[4], bfr[4];
            #pragma unroll
            for (int m = 0; m < 4; ++m) {
                int row = wr*64 + m*16 + r_l;
                af[m] = *reinterpret_cast<const short8v*>(
                    &As[row*64 + (((ks*4 + kg_l) ^ (row & 7)) << 3)]);
            }
            #pragma unroll
            for (int n = 0; n < 4; ++n) {
                int row = wc*64 + n*16 + r_l;
                bfr[n] = *reinterpret_cast<const short8v*>(
                    &Bs[row*64 + (((ks*4 + kg_l) ^ (row & 7)) << 3)]);
            }
            #pragma unroll
            for (int m = 0; m < 4; ++m)
                #pragma unroll
                for (int n = 0; n < 4; ++n)
                    acc[m][n] = __builtin_amdgcn_mfma_f32_16x16x32_bf16(af[m], bfr[n], acc[m][n], 0, 0, 0);
        }
        __syncthreads();
    }
}

__global__ __launch_bounds__(256)
void gemm_out_kernel(const unsigned short* __restrict__ Woutbf, const unsigned short* __restrict__ y,
                     const float* __restrict__ bout, float* __restrict__ out)
{
    __shared__ unsigned short lds[2 * 8192];
    int t = threadIdx.x;
    int m0 = blockIdx.y * 128;   // d tile
    int n0 = blockIdx.x * 128;   // pixel tile
    f32x4 acc[4][4] = {};
    gemm_mainloop(Woutbf, y, m0, n0, lds, lds + 8192, acc, t);

    int lane = t & 63;
    int wv = t >> 6, wr = wv >> 1, wc = wv & 1;
    int r_l = lane & 15, kg_l = lane >> 4;
    int nimg = n0 >> 12;
    int hwb = n0 & 4095;
    #pragma unroll
    for (int m = 0; m < 4; ++m) {
        int dbase = m0 + wr*64 + m*16 + (kg_l << 2);
        #pragma unroll
        for (int r = 0; r < 4; ++r) {
            int d = dbase + r;
            float bb = bout[d];
            #pragma unroll
            for (int n = 0; n < 4; ++n) {
                int pcol = wc*64 + n*16 + r_l;
                float z = acc[m][n][r] + bb;
                float sv = z / (1.f + __expf(-z));
                out[((size_t)(nimg*256 + d))*4096 + hwb + pcol] = sv;
            }
        }
    }
}

// ---------------- DCNv4 core: LDS-tiled value window ----------------
// Block = 16 px (one row segment) x 2 groups x 8 lanes. Stage 5x20 window
// (rows h-2..h+2, cols w0-2..w0+17, clamped) of 128 channels into LDS.
// Samples outside the window with nonzero weight fall back to global (rare).
__global__ __launch_bounds__(256)
void dcn_kernel(const unsigned short* __restrict__ VO, unsigned short* __restrict__ y)
{
    __shared__ unsigned short vt[5*20*128];   // 25600 B
    __shared__ float om_s[16][54];            // [px][g_l*27+k]
    int bid = blockIdx.x;
    int chunk = bid >> 1, gs = bid & 1;
    int p0 = chunk * 16;
    int n = p0 >> 12;
    int hw0 = p0 & 4095;
    int h = hw0 >> 6, w0 = hw0 & 63;
    int t = threadIdx.x;

    const unsigned short* vimg = VO + (size_t)n * (HW * (size_t)DALL);

    #pragma unroll
    for (int j = 0; j < 7; ++j) {
        int s = t + j*256;
        if (s < 1600) {
            int ch8 = s & 15;
            int cr = s >> 4;            // 0..99
            int col = cr % 20;
            int row = cr / 20;          // 0..4
            int vr = min(max(h - 2 + row, 0), 63);
            int vc = min(max(w0 - 2 + col, 0), 63);
            *reinterpret_cast<short8v*>(&vt[(row*20 + col)*128 + ch8*8]) =
                *reinterpret_cast<const short8v*>(
                    &vimg[(size_t)(vr*64 + vc)*DALL + gs*128 + ch8*8]);
        }
    }
    #pragma unroll
    for (int j = 0; j < 4; ++j) {
        int s = t + j*256;
        if (s < 864) {
            int pxl = s / 54;
            int r = s - pxl*54;
            om_s[pxl][r] = b2f(vimg[(size_t)(hw0 + pxl)*DALL + 256 + gs*54 + r]);
        }
    }
    __syncthreads();

    int slot = t >> 3, ch8 = t & 7;
    int pxl = slot >> 1, gl = slot & 1;
    int w = w0 + pxl;
    const float* o = om_s[pxl] + gl*27;
    const unsigned short* vgbase = vimg + gs*128 + gl*64 + ch8*8;

    f32x2 acc2[4] = {};
    #pragma unroll
    for (int k = 0; k < 9; ++k) {
        float dxo = o[2*k], dyo = o[2*k+1], m = o[18+k];
        float pxf = (float)(w + (k % 3) - 1) + dxo;
        float pyf = (float)(h + (k / 3) - 1) + dyo;
        float x0f = floorf(pxf), y0f = floorf(pyf);
        float fx = pxf - x0f, fy = pyf - y0f;
        int x0 = (int)x0f, y0 = (int)y0f;
        #pragma unroll
        for (int dyy = 0; dyy < 2; ++dyy) {
            #pragma unroll
            for (int dxx = 0; dxx < 2; ++dxx) {
                int yy = y0 + dyy, xx = x0 + dxx;
                bool valid = (yy >= 0) & (yy < HH) & (xx >= 0) & (xx < WW);
                float wgt = (dyy ? fy : 1.f - fy) * (dxx ? fx : 1.f - fx);
                float wmc = valid ? (m * wgt) : 0.f;
                int ry = yy - (h - 2), rx = xx - (w0 - 2);
                bool intile = ((unsigned)ry < 5u) & ((unsigned)rx < 20u);
                int4 v;
                if (intile | (wmc == 0.f)) {
                    int ryc = min(max(ry, 0), 4), rxc = min(max(rx, 0), 19);
                    v = *reinterpret_cast<const int4*>(&vt[(ryc*20 + rxc)*128 + gl*64 + ch8*8]);
                } else {
                    int yc = min(max(yy, 0), HH - 1);
                    int xc = min(max(xx, 0), WW - 1);
                    v = *reinterpret_cast<const int4*>(&vgbase[(size_t)(yc*64 + xc)*DALL]);
                }
                f32x2 wm2; wm2[0] = wmc; wm2[1] = wmc;
                int vv[4] = {v.x, v.y, v.z, v.w};
                #pragma unroll
                for (int q = 0; q < 4; ++q) {
                    f32x2 val2 = bf2x(vv[q]);
                    acc2[q] += val2 * wm2;
                }
            }
        }
    }
    short8v ov;
    #pragma unroll
    for (int q = 0; q < 4; ++q) {
        ov[2*q]   = (short)f2b(acc2[q][0]);
        ov[2*q+1] = (short)f2b(acc2[q][1]);
    }
    *reinterpret_cast<short8v*>(&y[(size_t)(p0+pxl)*256 + (gs*2+gl)*64 + ch8*8]) = ov;
}

extern "C" void kernel_launch(void* const* d_in, const int* in_sizes, int n_in,
                              void* d_out, int out_size, void* d_ws, size_t ws_size,
                              hipStream_t stream) {
    const float* x       = (const float*)d_in[0];
    const float* cv1_w   = (const float*)d_in[1];
    const float* cv1_b   = (const float*)d_in[2];
    const float* value_w = (const float*)d_in[3];
    const float* value_b = (const float*)d_in[4];
    const float* dw_w    = (const float*)d_in[5];
    const float* dw_b    = (const float*)d_in[6];
    const float* om_w    = (const float*)d_in[7];
    const float* om_b    = (const float*)d_in[8];
    const float* out_w   = (const float*)d_in[9];
    const float* cv2_w   = (const float*)d_in[10];
    const float* bn_g    = (const float*)d_in[11];
    const float* bn_b    = (const float*)d_in[12];
    const float* bn_m    = (const float*)d_in[13];
    const float* bn_v    = (const float*)d_in[14];

    char* ws = (char*)d_ws;
    unsigned short* VO     = (unsigned short*)(ws);
    unsigned short* y      = (unsigned short*)(ws + 25165824);
    unsigned short* Wallbf = (unsigned short*)(ws + 41943040);
    unsigned short* Woutbf = (unsigned short*)(ws + 42139648);
    float*          ball   = (float*)(ws + 42270720);
    float*          bout   = (float*)(ws + 42272256);
    float* out = (float*)d_out;

    prep_kernel<<<643, 256, 0, stream>>>(cv1_w, cv1_b, value_w, value_b, dw_w, dw_b,
                                         om_w, om_b, out_w, cv2_w,
                                         bn_g, bn_b, bn_m, bn_v,
                                         Wallbf, ball, Woutbf, bout);
    gemm_vo_kernel<<<dim3(256, 3), 256, 0, stream>>>(x, Wallbf, ball, VO);
    dcn_kernel<<<4096, 256, 0, stream>>>(VO, y);
    gemm_out_kernel<<<dim3(256, 2), 256, 0, stream>>>(Woutbf, y, bout, out);
}

// Round 5
// 92.420 us; speedup vs baseline: 1.3417x; 1.3417x over previous
//
#include <hip/hip_runtime.h>
#include <hip/hip_bf16.h>
#include <math.h>

#define NN    8
#define HH    64
#define WW    64
#define HW    4096
#define NHW   32768
#define DALL  384     // 256 value + 112 om + 16 pad
#define EPSBN 1e-5f

typedef __attribute__((ext_vector_type(8))) short short8v;
typedef __attribute__((ext_vector_type(4))) float f32x4;
typedef __attribute__((ext_vector_type(2))) float f32x2;

__device__ __forceinline__ float b2f(unsigned short u) {
    union { unsigned int i; float f; } v; v.i = ((unsigned int)u) << 16; return v.f;
}
__device__ __forceinline__ unsigned short f2b(float f) {
    __hip_bfloat16 h = __float2bfloat16(f);
    return *reinterpret_cast<const unsigned short*>(&h);
}
// dword of 2 bf16 -> f32x2 (lo, hi)
__device__ __forceinline__ f32x2 bf2x(int u) {
    union { int i; float f; } a, b;
    a.i = u << 16;
    b.i = u & 0xffff0000;
    f32x2 r; r[0] = a.f; r[1] = b.f; return r;
}

// Workspace layout (bytes):
//  VO     [NHW][384] bf16  @ 0          (25165824)
//  y      [NHW][256] bf16  @ 25165824   (16777216)
//  Wallbf [384][256] bf16  @ 41943040   (196608)
//  Woutbf [256][256] bf16  @ 42139648   (131072)
//  ball   [384] f32        @ 42270720   (1536)
//  bout   [256] f32        @ 42272256   (1024)

// ---------------- prep: fold weights (f32 math, 4-way ILP) ----------------
__global__ __launch_bounds__(256)
void prep_kernel(const float* __restrict__ cv1_w, const float* __restrict__ cv1_b,
                 const float* __restrict__ value_w, const float* __restrict__ value_b,
                 const float* __restrict__ dw_w, const float* __restrict__ dw_b,
                 const float* __restrict__ om_w, const float* __restrict__ om_b,
                 const float* __restrict__ out_w, const float* __restrict__ cv2_w,
                 const float* __restrict__ bn_g, const float* __restrict__ bn_b,
                 const float* __restrict__ bn_m, const float* __restrict__ bn_v,
                 unsigned short* __restrict__ Wallbf, float* __restrict__ ball,
                 unsigned short* __restrict__ Woutbf, float* __restrict__ bout)
{
    int job = blockIdx.x * 256 + threadIdx.x;
    if (job < 65536) {                          // Wv = value_w @ cv1_w
        int d = job >> 8, cc = job & 255;
        float s0=0.f, s1=0.f, s2=0.f, s3=0.f;
        for (int e = 0; e < 256; e += 4) {
            float4 wv = *reinterpret_cast<const float4*>(&value_w[d*256+e]);
            s0 = fmaf(wv.x, cv1_w[(e+0)*256+cc], s0);
            s1 = fmaf(wv.y, cv1_w[(e+1)*256+cc], s1);
            s2 = fmaf(wv.z, cv1_w[(e+2)*256+cc], s2);
            s3 = fmaf(wv.w, cv1_w[(e+3)*256+cc], s3);
        }
        Wallbf[job] = f2b((s0+s1)+(s2+s3));
    } else if (job < 94208) {                   // Wom = om_w.diag(dw_w) @ cv1_w
        int idx = job - 65536;
        int o = idx >> 8, cc = idx & 255;
        float s0=0.f, s1=0.f, s2=0.f, s3=0.f;
        for (int e = 0; e < 256; e += 4) {
            float4 wv = *reinterpret_cast<const float4*>(&om_w[o*256+e]);
            float4 dv = *reinterpret_cast<const float4*>(&dw_w[e]);
            s0 = fmaf(wv.x*dv.x, cv1_w[(e+0)*256+cc], s0);
            s1 = fmaf(wv.y*dv.y, cv1_w[(e+1)*256+cc], s1);
            s2 = fmaf(wv.z*dv.z, cv1_w[(e+2)*256+cc], s2);
            s3 = fmaf(wv.w*dv.w, cv1_w[(e+3)*256+cc], s3);
        }
        Wallbf[job] = f2b((s0+s1)+(s2+s3));
    } else if (job < 98304) {                   // pad rows 368..383
        Wallbf[job] = 0;
    } else if (job < 163840) {                  // Wout = diag(s) cv2_w @ out_w
        int idx = job - 98304;
        int d = idx >> 8, cc = idx & 255;
        float s0=0.f, s1=0.f, s2=0.f, s3=0.f;
        for (int e = 0; e < 256; e += 4) {
            float4 wv = *reinterpret_cast<const float4*>(&cv2_w[d*256+e]);
            s0 = fmaf(wv.x, out_w[(e+0)*256+cc], s0);
            s1 = fmaf(wv.y, out_w[(e+1)*256+cc], s1);
            s2 = fmaf(wv.z, out_w[(e+2)*256+cc], s2);
            s3 = fmaf(wv.w, out_w[(e+3)*256+cc], s3);
        }
        float sc = bn_g[d] * rsqrtf(bn_v[d] + EPSBN);
        Woutbf[idx] = f2b(((s0+s1)+(s2+s3)) * sc);
    } else if (job < 164096) {                  // bv
        int d = job - 163840;
        float s = value_b[d];
        for (int e = 0; e < 256; ++e) s = fmaf(value_w[d*256+e], cv1_b[e], s);
        ball[d] = s;
    } else if (job < 164208) {                  // bom
        int o = job - 164096;
        float s = om_b[o];
        for (int e = 0; e < 256; ++e)
            s = fmaf(om_w[o*256+e], fmaf(dw_w[e], cv1_b[e], dw_b[e]), s);
        ball[256 + o] = s;
    } else if (job < 164224) {                  // ball pad
        ball[368 + job - 164208] = 0.f;
    } else if (job < 164480) {                  // bout
        int d = job - 164224;
        float sc = bn_g[d] * rsqrtf(bn_v[d] + EPSBN);
        bout[d] = fmaf(-bn_m[d], sc, bn_b[d]);
    }
}

// ---------------- GEMM1 (fused x-transpose): VO = bf16(x)^T @ Wallbf^T + ball ----------------
__global__ __launch_bounds__(256)
void gemm_vo_kernel(const float* __restrict__ x, const unsigned short* __restrict__ Wallbf,
                    const float* __restrict__ ball, unsigned short* __restrict__ VO)
{
    __shared__ unsigned short As[8192];
    __shared__ unsigned short Bs[8192];
    int t = threadIdx.x;
    int m0 = blockIdx.x * 128;   // pixel tile
    int n0 = blockIdx.y * 128;   // output-channel tile
    int nimg = m0 >> 12, hw0 = m0 & 4095;
    int lane = t & 63;
    int wv = t >> 6;
    int wr = wv >> 1, wc = wv & 1;
    int r_l = lane & 15, kg_l = lane >> 4;
    int ci = t >> 6;             // c-chunk (16 ch) for A staging
    int l  = t & 63;             // row-pair for A staging

    const float* xbase = x + (size_t)(nimg * 256) * 4096 + hw0;

    f32x4 acc[4][4] = {};

    for (int kt = 0; kt < 4; ++kt) {
        int c0 = kt * 64;
        float2 val[16];
        #pragma unroll
        for (int i = 0; i < 16; ++i)
            val[i] = *reinterpret_cast<const float2*>(
                &xbase[(size_t)(c0 + ci*16 + i) * 4096 + 2*l]);
        __syncthreads();   // prior MFMA reads done before overwrite
        #pragma unroll
        for (int rsel = 0; rsel < 2; ++rsel) {
            int row = 2*l + rsel;
            #pragma unroll
            for (int kgi = 0; kgi < 2; ++kgi) {
                int kg = ci*2 + kgi;
                short8v s;
                #pragma unroll
                for (int j = 0; j < 8; ++j)
                    s[j] = (short)f2b(rsel ? val[kgi*8+j].y : val[kgi*8+j].x);
                *reinterpret_cast<short8v*>(&As[row*64 + ((kg ^ (row & 7)) << 3)]) = s;
            }
        }
        #pragma unroll
        for (int i = 0; i < 4; ++i) {
            int idx = t + i*256;
            int row = idx >> 3, kg = idx & 7;
            *reinterpret_cast<short8v*>(&Bs[row*64 + ((kg ^ (row & 7)) << 3)]) =
                *reinterpret_cast<const short8v*>(&Wallbf[(size_t)(n0 + row)*256 + c0 + kg*8]);
        }
        __syncthreads();
        #pragma unroll
        for (int ks = 0; ks < 2; ++ks) {
            short8v af[4], bfr[4];
            #pragma unroll
            for (int m = 0; m < 4; ++m) {
                int row = wr*64 + m*16 + r_l;
                af[m] = *reinterpret_cast<const short8v*>(
                    &As[row*64 + (((ks*4 + kg_l) ^ (row & 7)) << 3)]);
            }
            #pragma unroll
            for (int n = 0; n < 4; ++n) {
                int row = wc*64 + n*16 + r_l;
                bfr[n] = *reinterpret_cast<const short8v*>(
                    &Bs[row*64 + (((ks*4 + kg_l) ^ (row & 7)) << 3)]);
            }
            #pragma unroll
            for (int m = 0; m < 4; ++m)
                #pragma unroll
                for (int n = 0; n < 4; ++n)
                    acc[m][n] = __builtin_amdgcn_mfma_f32_16x16x32_bf16(af[m], bfr[n], acc[m][n], 0, 0, 0);
        }
    }

    #pragma unroll
    for (int n = 0; n < 4; ++n) {
        int d = n0 + wc*64 + n*16 + r_l;
        float bb = ball[d];
        #pragma unroll
        for (int m = 0; m < 4; ++m) {
            int pr = m0 + wr*64 + m*16 + (kg_l << 2);
            #pragma unroll
            for (int r = 0; r < 4; ++r)
                VO[(size_t)(pr + r)*384 + d] = f2b(acc[m][n][r] + bb);
        }
    }
}

// ---------------- shared MFMA mainloop (for GEMM2) ----------------
__device__ __forceinline__
void gemm_mainloop(const unsigned short* __restrict__ A, const unsigned short* __restrict__ B,
                   int m0, int n0, unsigned short* As, unsigned short* Bs,
                   f32x4 (&acc)[4][4], int t)
{
    int lane = t & 63;
    int wv = t >> 6;
    int wr = wv >> 1, wc = wv & 1;
    int r_l = lane & 15;
    int kg_l = lane >> 4;

    for (int kt = 0; kt < 4; ++kt) {
        int c0 = kt * 64;
        #pragma unroll
        for (int i = 0; i < 4; ++i) {
            int idx = t + i * 256;
            int kg = idx & 7, row = idx >> 3;
            int soff = row*64 + ((kg ^ (row & 7)) << 3);
            *reinterpret_cast<short8v*>(&As[soff]) =
                *reinterpret_cast<const short8v*>(&A[(size_t)(m0 + row)*256 + c0 + kg*8]);
            *reinterpret_cast<short8v*>(&Bs[soff]) =
                *reinterpret_cast<const short8v*>(&B[(size_t)(n0 + row)*256 + c0 + kg*8]);
        }
        __syncthreads();
        #pragma unroll
        for (int ks = 0; ks < 2; ++ks) {
            short8v af[4], bfr[4];
            #pragma unroll
            for (int m = 0; m < 4; ++m) {
                int row = wr*64 + m*16 + r_l;
                af[m] = *reinterpret_cast<const short8v*>(
                    &As[row*64 + (((ks*4 + kg_l) ^ (row & 7)) << 3)]);
            }
            #pragma unroll
            for (int n = 0; n < 4; ++n) {
                int row = wc*64 + n*16 + r_l;
                bfr[n] = *reinterpret_cast<const short8v*>(
                    &Bs[row*64 + (((ks*4 + kg_l) ^ (row & 7)) << 3)]);
            }
            #pragma unroll
            for (int m = 0; m < 4; ++m)
                #pragma unroll
                for (int n = 0; n < 4; ++n)
                    acc[m][n] = __builtin_amdgcn_mfma_f32_16x16x32_bf16(af[m], bfr[n], acc[m][n], 0, 0, 0);
        }
        __syncthreads();
    }
}

// ---------------- GEMM2 (transposed): out = SiLU(Wout @ y^T + bout), NCHW f32 ----------------
__global__ __launch_bounds__(256)
void gemm_out_kernel(const unsigned short* __restrict__ Woutbf, const unsigned short* __restrict__ y,
                     const float* __restrict__ bout, float* __restrict__ out)
{
    __shared__ unsigned short lds[2 * 8192];
    int t = threadIdx.x;
    int m0 = blockIdx.y * 128;   // d tile
    int n0 = blockIdx.x * 128;   // pixel tile
    f32x4 acc[4][4] = {};
    gemm_mainloop(Woutbf, y, m0, n0, lds, lds + 8192, acc, t);

    int lane = t & 63;
    int wv = t >> 6, wr = wv >> 1, wc = wv & 1;
    int r_l = lane & 15, kg_l = lane >> 4;
    int nimg = n0 >> 12;
    int hwb = n0 & 4095;
    #pragma unroll
    for (int m = 0; m < 4; ++m) {
        int dbase = m0 + wr*64 + m*16 + (kg_l << 2);
        #pragma unroll
        for (int r = 0; r < 4; ++r) {
            int d = dbase + r;
            float bb = bout[d];
            #pragma unroll
            for (int n = 0; n < 4; ++n) {
                int pcol = wc*64 + n*16 + r_l;
                float z = acc[m][n][r] + bb;
                float sv = z / (1.f + __expf(-z));
                out[((size_t)(nimg*256 + d))*4096 + hwb + pcol] = sv;
            }
        }
    }
}

// ---------------- DCNv4 core: 8 ch/lane, direct global loads, pk-f32x2 accum ----------------
__global__ __launch_bounds__(256)
void dcn_kernel(const unsigned short* __restrict__ VO, unsigned short* __restrict__ y)
{
    __shared__ float om_s[8][108];
    int t = threadIdx.x;
    int p0 = blockIdx.x * 8;

    for (int i = t; i < 864; i += 256) {
        int pl = i / 108, j = i - pl * 108;
        om_s[pl][j] = b2f(VO[(size_t)(p0 + pl)*384 + 256 + j]);
    }
    __syncthreads();

    int slot = t >> 3, ch8 = t & 7;
    int pl = slot >> 2, g = slot & 3;
    int p = p0 + pl;
    int hw = p & 4095;
    int h = hw >> 6, w = hw & 63;
    const unsigned short* vbase = VO + (size_t)(p >> 12) * (HW * (size_t)DALL) + g*64 + ch8*8;
    const float* o = &om_s[pl][g*27];

    f32x2 acc2[4] = {};
    #pragma unroll
    for (int k = 0; k < 9; ++k) {
        float dxo = o[2*k], dyo = o[2*k+1], m = o[18+k];
        float pxf = (float)(w + (k % 3) - 1) + dxo;
        float pyf = (float)(h + (k / 3) - 1) + dyo;
        float x0f = floorf(pxf), y0f = floorf(pyf);
        float fx = pxf - x0f, fy = pyf - y0f;
        int x0 = (int)x0f, y0 = (int)y0f;
        #pragma unroll
        for (int dyy = 0; dyy < 2; ++dyy) {
            #pragma unroll
            for (int dxx = 0; dxx < 2; ++dxx) {
                int yy = y0 + dyy, xx = x0 + dxx;
                bool valid = (yy >= 0) & (yy < HH) & (xx >= 0) & (xx < WW);
                float wgt = (dyy ? fy : 1.f - fy) * (dxx ? fx : 1.f - fx);
                float wmc = valid ? (m * wgt) : 0.f;
                int yc = min(max(yy, 0), HH - 1);
                int xc = min(max(xx, 0), WW - 1);
                int4 v = *reinterpret_cast<const int4*>(
                    &vbase[(size_t)(yc * WW + xc) * DALL]);
                f32x2 wm2; wm2[0] = wmc; wm2[1] = wmc;
                int vv[4] = {v.x, v.y, v.z, v.w};
                #pragma unroll
                for (int q = 0; q < 4; ++q)
                    acc2[q] += bf2x(vv[q]) * wm2;
            }
        }
    }
    short8v ov;
    #pragma unroll
    for (int q = 0; q < 4; ++q) {
        ov[2*q]   = (short)f2b(acc2[q][0]);
        ov[2*q+1] = (short)f2b(acc2[q][1]);
    }
    *reinterpret_cast<short8v*>(&y[(size_t)p*256 + g*64 + ch8*8]) = ov;
}

extern "C" void kernel_launch(void* const* d_in, const int* in_sizes, int n_in,
                              void* d_out, int out_size, void* d_ws, size_t ws_size,
                              hipStream_t stream) {
    const float* x       = (const float*)d_in[0];
    const float* cv1_w   = (const float*)d_in[1];
    const float* cv1_b   = (const float*)d_in[2];
    const float* value_w = (const float*)d_in[3];
    const float* value_b = (const float*)d_in[4];
    const float* dw_w    = (const float*)d_in[5];
    const float* dw_b    = (const float*)d_in[6];
    const float* om_w    = (const float*)d_in[7];
    const float* om_b    = (const float*)d_in[8];
    const float* out_w   = (const float*)d_in[9];
    const float* cv2_w   = (const float*)d_in[10];
    const float* bn_g    = (const float*)d_in[11];
    const float* bn_b    = (const float*)d_in[12];
    const float* bn_m    = (const float*)d_in[13];
    const float* bn_v    = (const float*)d_in[14];

    char* ws = (char*)d_ws;
    unsigned short* VO     = (unsigned short*)(ws);
    unsigned short* y      = (unsigned short*)(ws + 25165824);
    unsigned short* Wallbf = (unsigned short*)(ws + 41943040);
    unsigned short* Woutbf = (unsigned short*)(ws + 42139648);
    float*          ball   = (float*)(ws + 42270720);
    float*          bout   = (float*)(ws + 42272256);
    float* out = (float*)d_out;

    prep_kernel<<<643, 256, 0, stream>>>(cv1_w, cv1_b, value_w, value_b, dw_w, dw_b,
                                         om_w, om_b, out_w, cv2_w,
                                         bn_g, bn_b, bn_m, bn_v,
                                         Wallbf, ball, Woutbf, bout);
    gemm_vo_kernel<<<dim3(256, 3), 256, 0, stream>>>(x, Wallbf, ball, VO);
    dcn_kernel<<<4096, 256, 0, stream>>>(VO, y);
    gemm_out_kernel<<<dim3(256, 2), 256, 0, stream>>>(Woutbf, y, bout, out);
}